// Round 8
// baseline (130.936 us; speedup 1.0000x reference)
//
#include <hip/hip_runtime.h>
#include <stdint.h>

#define BATCH    8
#define NITEMS   1000000
#define NC       64            // coarse value bins: floor(s*64)
#define NF       4096          // fine bins within boundary coarse bin
#define NBLKA    512           // blocks/batch for stream kernels
#define STRIDE   (NBLKA * 256) // 131072
#define UNROLL   8
#define BUFCAP   1024          // per-block LDS candidate buffer
#define CANDCAP  131072        // per-batch clist capacity (fast path)
#define CANDCAP2 262144        // per-batch clist2 capacity (fallback)
#define CAP      32768         // per-batch cand capacity
#define IMG_W    768.0f
#define IMG_H    432.0f

typedef unsigned long long ull;

static __device__ __forceinline__ float clip0(float v, float hi) {
    return fminf(fmaxf(v, 0.0f), hi);
}
static __device__ __forceinline__ int cbin(float s) {
    int g = (int)(s * (float)NC);                   // pow-2 mul: exact, monotone
    return g > NC - 1 ? NC - 1 : (g < 0 ? 0 : g);
}
static __device__ __forceinline__ int fbin(float s, int g) {
    int f = (int)(s * (float)(NC * NF)) - g * NF;   // pow-2 mul: exact, monotone
    return f > NF - 1 ? NF - 1 : (f < 0 ? 0 : f);
}
static __device__ __forceinline__ unsigned mkbits(float4 box, float s) {
    float x1 = clip0(box.x - box.z * 0.5f, IMG_W);
    float x2 = clip0(box.x + box.z * 0.5f, IMG_W);
    float y1 = clip0(box.y - box.w * 0.5f, IMG_H);
    float y2 = clip0(box.y + box.w * 0.5f, IMG_H);
    bool m = ((x2 - x1) > 16.0f) && ((y2 - y1) > 16.0f);
    return __float_as_uint(m ? s : 0.0f);
}

// ---- kernel 1: near-copy stream. coarse hist + ballot-append of top-2 bins ----
__global__ __launch_bounds__(256)
void k_stream(const float* __restrict__ scores,
              const float4* __restrict__ rps,
              unsigned short* __restrict__ p1,
              ull* __restrict__ clist,
              unsigned* __restrict__ rawCnt,
              unsigned* __restrict__ ovf) {
    __shared__ unsigned h1[4][NC];
    __shared__ ull buf[BUFCAP];
    __shared__ unsigned blkCnt, gBase;
    const int b = blockIdx.y, blk = blockIdx.x, tid = threadIdx.x;
    const int wave = tid >> 6, lane = tid & 63;
    if (tid < NC) { h1[0][tid]=0u; h1[1][tid]=0u; h1[2][tid]=0u; h1[3][tid]=0u; }
    if (tid == 0) blkCnt = 0u;
    __syncthreads();
    const size_t base = (size_t)b * NITEMS;
    const float*  sp = scores + base;
    const float4* rp = rps + base;
    const int j0 = blk * 256 + tid;
    float  sv[UNROLL];
    float4 bv[UNROLL];
    #pragma unroll
    for (int k = 0; k < UNROLL; ++k) {           // lane-contiguous, 16 loads in flight
        int j = j0 + k * STRIDE;
        if (j < NITEMS) { sv[k] = sp[j]; bv[k] = rp[j]; }
    }
    #pragma unroll
    for (int k = 0; k < UNROLL; ++k) {
        int j = j0 + k * STRIDE;
        unsigned bits = 0u;
        if (j < NITEMS) bits = mkbits(bv[k], sv[k]);
        int g = -1;
        if (bits) { g = cbin(__uint_as_float(bits)); atomicAdd(&h1[wave][g], 1u); }
        bool q = (g >= NC - 2);
        ull m = __ballot(q);
        if (m) {
            unsigned cnt = (unsigned)__popcll(m);
            unsigned pre = (unsigned)__popcll(m & ((1ULL << lane) - 1ULL));
            int leader = __ffsll((long long)m) - 1;
            unsigned bse = 0;
            if (lane == leader) bse = atomicAdd(&blkCnt, cnt);
            bse = (unsigned)__shfl((int)bse, leader);
            if (q) {
                unsigned s2 = bse + pre;
                if (s2 < BUFCAP)
                    buf[s2] = ((ull)bits << 32) | (unsigned)(~(unsigned)j);
            }
        }
    }
    __syncthreads();
    if (tid < NC)
        p1[(size_t)(b * NBLKA + blk) * NC + tid] =
            (unsigned short)(h1[0][tid] + h1[1][tid] + h1[2][tid] + h1[3][tid]);
    unsigned n = blkCnt;
    if (n > BUFCAP) { if (tid == 0) atomicOr(&ovf[b], 1u); n = BUFCAP; }
    if (tid == 0) gBase = atomicAdd(&rawCnt[b], n);
    __syncthreads();
    const unsigned gb = gBase;
    for (unsigned t = tid; t < n; t += 256) {
        unsigned slot = gb + t;
        if (slot < CANDCAP) clist[(size_t)b * CANDCAP + slot] = buf[t];
    }
}

// ---- scan1: reduce 512 coarse rows + serial suffix scan; set fast flag ----
__global__ __launch_bounds__(256)
void k_scan1(const unsigned short* __restrict__ p1,
             const unsigned* __restrict__ rawCnt,
             const unsigned* __restrict__ ovf,
             unsigned* __restrict__ chist64,
             unsigned* __restrict__ csuf64,
             unsigned* __restrict__ ctrA,
             unsigned* __restrict__ meta,
             int K) {
    const int b = blockIdx.x, tid = threadIdx.x;
    __shared__ unsigned sm[256];
    const int bin = tid & 63, chunk = tid >> 6;     // 4 chunks x 128 rows
    unsigned s = 0;
    for (int k = chunk * 128; k < chunk * 128 + 128; ++k)
        s += p1[(size_t)(b * NBLKA + k) * NC + bin];
    sm[tid] = s;
    __syncthreads();
    if (tid < NC) sm[tid] = sm[tid] + sm[64 + tid] + sm[128 + tid] + sm[192 + tid];
    __syncthreads();
    if (tid == 0) {
        unsigned run = 0, cbb = 0, nAb = 0;
        bool found = false;
        for (int g = NC - 1; g >= 0; --g) {
            unsigned c = sm[g];
            chist64[b * NC + g] = c;
            csuf64[b * NC + g] = run;
            if (!found && run < (unsigned)K && run + c >= (unsigned)K) {
                cbb = (unsigned)g; nAb = run; found = true;
            }
            run += c;
        }
        meta[b * 8 + 0] = cbb;
        meta[b * 8 + 1] = nAb;
        meta[b * 8 + 4] = (found && cbb >= (unsigned)(NC - 2) && ovf[b] == 0u &&
                           rawCnt[b] <= (unsigned)CANDCAP) ? 1u : 0u;
    }
    if (tid < NC) ctrA[b * NC + tid] = 0u;
}

// ---- fallback stream: only when fast path invalid (early-exit otherwise) ----
__global__ __launch_bounds__(256)
void k_fb(const float* __restrict__ scores,
          const float4* __restrict__ rps,
          const unsigned* __restrict__ meta,
          ull* __restrict__ clist2,
          unsigned* __restrict__ rawCnt2) {
    const int b = blockIdx.y;
    if (meta[b * 8 + 4]) return;
    __shared__ ull buf[BUFCAP];
    __shared__ unsigned blkCnt, gBase;
    const int blk = blockIdx.x, tid = threadIdx.x;
    const int lane = tid & 63;
    const int cbb = (int)meta[b * 8 + 0];
    if (tid == 0) blkCnt = 0u;
    __syncthreads();
    const size_t base = (size_t)b * NITEMS;
    const float*  sp = scores + base;
    const float4* rp = rps + base;
    const int j0 = blk * 256 + tid;
    #pragma unroll
    for (int k = 0; k < UNROLL; ++k) {
        int j = j0 + k * STRIDE;
        unsigned bits = 0u;
        if (j < NITEMS) bits = mkbits(rp[j], sp[j]);
        bool q = false;
        if (bits) q = (cbin(__uint_as_float(bits)) >= cbb);
        ull m = __ballot(q);
        if (m) {
            unsigned cnt = (unsigned)__popcll(m);
            unsigned pre = (unsigned)__popcll(m & ((1ULL << lane) - 1ULL));
            int leader = __ffsll((long long)m) - 1;
            unsigned bse = 0;
            if (lane == leader) bse = atomicAdd(&blkCnt, cnt);
            bse = (unsigned)__shfl((int)bse, leader);
            if (q) {
                unsigned s2 = bse + pre;
                if (s2 < BUFCAP)
                    buf[s2] = ((ull)bits << 32) | (unsigned)(~(unsigned)j);
            }
        }
    }
    __syncthreads();
    unsigned n = blkCnt > BUFCAP ? BUFCAP : blkCnt;
    if (tid == 0) gBase = atomicAdd(&rawCnt2[b], n);
    __syncthreads();
    const unsigned gb = gBase;
    for (unsigned t = tid; t < n; t += 256) {
        unsigned slot = gb + t;
        if (slot < CANDCAP2) clist2[(size_t)b * CANDCAP2 + slot] = buf[t];
    }
}

// ---- fine hist of boundary bin from candidate list ----
__global__ __launch_bounds__(1024)
void k_fine(const ull* __restrict__ clist,
            const ull* __restrict__ clist2,
            const unsigned* __restrict__ rawCnt,
            const unsigned* __restrict__ rawCnt2,
            const unsigned* __restrict__ meta,
            unsigned* __restrict__ red2) {
    const int b = blockIdx.x, tid = threadIdx.x;
    __shared__ unsigned h2[NF];
    for (int k = tid; k < NF; k += 1024) h2[k] = 0u;
    __syncthreads();
    const unsigned fast = meta[b * 8 + 4];
    const unsigned cbb = meta[b * 8 + 0];
    const ull* src = fast ? clist + (size_t)b * CANDCAP : clist2 + (size_t)b * CANDCAP2;
    unsigned N = fast ? rawCnt[b] : rawCnt2[b];
    const unsigned capN = fast ? CANDCAP : CANDCAP2;
    if (N > capN) N = capN;
    for (unsigned i = tid; i < N; i += 1024) {
        unsigned bits = (unsigned)(src[i] >> 32);
        float s = __uint_as_float(bits);
        if ((unsigned)cbin(s) == cbb) atomicAdd(&h2[fbin(s, (int)cbb)], 1u);
    }
    __syncthreads();
    for (int k = tid; k < NF; k += 1024) red2[b * NF + k] = h2[k];
}

// ---- scan2: parallel suffix scan over 4096 fine bins ----
__global__ __launch_bounds__(1024)
void k_scan2(const unsigned* __restrict__ red2,
             unsigned* __restrict__ fhist,
             unsigned* __restrict__ fsuf,
             unsigned* __restrict__ ctrB,
             unsigned* __restrict__ meta,
             int K) {
    const int b = blockIdx.x, tid = threadIdx.x;
    __shared__ unsigned sc[1024];
    const int binbase = 4 * (1023 - tid);
    const uint4 v = *(const uint4*)(red2 + b * NF + binbase);
    unsigned cw[4] = {v.w, v.z, v.y, v.x};
    unsigned pin[4];
    unsigned run = 0;
    #pragma unroll
    for (int k = 0; k < 4; k++) { run += cw[k]; pin[k] = run; }
    sc[tid] = run;
    __syncthreads();
    unsigned x = run;
    for (int off = 1; off < 1024; off <<= 1) {
        unsigned t = (tid >= off) ? sc[tid - off] : 0u;
        __syncthreads();
        x += t;
        sc[tid] = x;
        __syncthreads();
    }
    const unsigned exclBase = x - run;
    const unsigned nAb = meta[b * 8 + 1];
    #pragma unroll
    for (int k = 0; k < 4; k++) {
        int g = binbase + (3 - k);
        unsigned excl = exclBase + pin[k] - cw[k];
        fsuf[b * NF + g] = excl;
        fhist[b * NF + g] = cw[k];
        unsigned t0 = nAb + excl;
        if (t0 < (unsigned)K && t0 + cw[k] >= (unsigned)K) {
            meta[b * 8 + 2] = (unsigned)g;
            meta[b * 8 + 3] = t0 + cw[k];
        }
    }
    if (tid == 0 && nAb + sc[1023] < (unsigned)K) {
        meta[b * 8 + 2] = 0u;
        meta[b * 8 + 3] = nAb + sc[1023];
    }
    ctrB[b * NF + tid * 4 + 0] = 0u;
    ctrB[b * NF + tid * 4 + 1] = 0u;
    ctrB[b * NF + tid * 4 + 2] = 0u;
    ctrB[b * NF + tid * 4 + 3] = 0u;
}

// ---- compact candidate list into segmented slots ----
__global__ __launch_bounds__(256)
void k_compact(const ull* __restrict__ clist,
               const ull* __restrict__ clist2,
               const unsigned* __restrict__ rawCnt,
               const unsigned* __restrict__ rawCnt2,
               const unsigned* __restrict__ meta,
               const unsigned* __restrict__ csuf64,
               const unsigned* __restrict__ fsuf,
               unsigned* __restrict__ ctrA,
               unsigned* __restrict__ ctrB,
               ull* __restrict__ cand) {
    const int b = blockIdx.y;
    const unsigned fast = meta[b * 8 + 4];
    const unsigned cbb = meta[b * 8 + 0];
    const unsigned nAb = meta[b * 8 + 1];
    const unsigned fb  = meta[b * 8 + 2];
    const ull* src = fast ? clist + (size_t)b * CANDCAP : clist2 + (size_t)b * CANDCAP2;
    unsigned N = fast ? rawCnt[b] : rawCnt2[b];
    const unsigned capN = fast ? CANDCAP : CANDCAP2;
    if (N > capN) N = capN;
    for (unsigned i = blockIdx.x * 256 + threadIdx.x; i < N; i += gridDim.x * 256) {
        const ull key = src[i];
        unsigned bits = (unsigned)(key >> 32);
        float s = __uint_as_float(bits);
        int g = cbin(s);
        if ((unsigned)g < cbb) continue;
        unsigned slot;
        if ((unsigned)g > cbb) {
            slot = csuf64[b * NC + g] + atomicAdd(&ctrA[b * NC + g], 1u);
        } else {
            int f = fbin(s, g);
            if ((unsigned)f < fb) continue;
            slot = nAb + fsuf[b * NF + f] + atomicAdd(&ctrB[b * NF + f], 1u);
        }
        if (slot < CAP) cand[(size_t)b * CAP + slot] = key;
    }
}

// ---- rank within tiny segment, gather, write outputs ----
__global__ __launch_bounds__(256)
void k_rank_out(const ull* __restrict__ cand,
                const unsigned* __restrict__ meta,
                const unsigned* __restrict__ csuf64,
                const unsigned* __restrict__ chist64,
                const unsigned* __restrict__ fsuf,
                const unsigned* __restrict__ fhist,
                const float4* __restrict__ rps,
                float* __restrict__ out,
                int K) {
    const int b = blockIdx.y;
    unsigned total = meta[b * 8 + 3];
    if (total > CAP) total = CAP;
    const unsigned p = blockIdx.x * 256 + threadIdx.x;
    if (p >= total) return;
    const ull key = cand[(size_t)b * CAP + p];
    const unsigned bits = (unsigned)(key >> 32);
    const float s = __uint_as_float(bits);
    const unsigned cbb = meta[b * 8 + 0];
    const unsigned nAb = meta[b * 8 + 1];
    int g = cbin(s);
    unsigned sbase, scnt;
    if ((unsigned)g > cbb) {
        sbase = csuf64[b * NC + g];
        scnt  = chist64[b * NC + g];
    } else {
        int f = fbin(s, g);
        sbase = nAb + fsuf[b * NF + f];
        scnt  = fhist[b * NF + f];
    }
    unsigned send = sbase + scnt;
    if (send > total) send = total;
    unsigned rank = sbase;
    for (unsigned j = sbase; j < send; j++)
        rank += (cand[(size_t)b * CAP + j] > key) ? 1u : 0u;
    if (rank < (unsigned)K) {
        unsigned idx = ~((unsigned)key);
        if (idx >= (unsigned)NITEMS) idx = 0;       // never fault on a bad slot
        float4 box = rps[(size_t)b * NITEMS + idx];
        float x1 = clip0(box.x - box.z * 0.5f, IMG_W);
        float x2 = clip0(box.x + box.z * 0.5f, IMG_W);
        float y1 = clip0(box.y - box.w * 0.5f, IMG_H);
        float y2 = clip0(box.y + box.w * 0.5f, IMG_H);
        float nw = x2 - x1, nh = y2 - y1;
        float nx = x1 + nw * 0.5f, ny = y1 + nh * 0.5f;
        ((float4*)out)[(size_t)b * K + rank] = make_float4(nx, ny, nw, nh);
        out[(size_t)BATCH * K * 4 + (size_t)b * K + rank] = s;
    }
}

extern "C" void kernel_launch(void* const* d_in, const int* in_sizes, int n_in,
                              void* d_out, int out_size, void* d_ws, size_t ws_size,
                              hipStream_t stream) {
    const float*  scores = (const float*)d_in[0];
    const float4* rps    = (const float4*)d_in[1];
    const int K = out_size / (BATCH * 5);               // 12000

    // ---- workspace layout (non-overlapping, verified sizes) ----
    uint8_t* w = (uint8_t*)d_ws;
    unsigned short* p1 = (unsigned short*)(w);             //         0 + 524,288
    unsigned* red2     = (unsigned*)(w +    600000);       //   600,000 + 131,072
    unsigned* chist64  = (unsigned*)(w +    740000);       //   740,000 +   2,048
    unsigned* csuf64   = (unsigned*)(w +    744000);       //   744,000 +   2,048
    unsigned* ctrA     = (unsigned*)(w +    748000);       //   748,000 +   2,048
    unsigned* fhist    = (unsigned*)(w +    760000);       //   760,000 + 131,072
    unsigned* fsuf     = (unsigned*)(w +    900000);       //   900,000 + 131,072
    unsigned* ctrB     = (unsigned*)(w +   1040000);       // 1,040,000 + 131,072
    unsigned* meta     = (unsigned*)(w +   1180000);       // 1,180,000 +     256
    unsigned* rawCnt   = (unsigned*)(w +   1181024);       // ┐
    unsigned* rawCnt2  = (unsigned*)(w +   1181056);       // │ one 96-B memset
    unsigned* ovf      = (unsigned*)(w +   1181088);       // ┘
    ull* cand          = (ull*)(w +       1200000);        // 1,200,000 + 2 MiB
    ull* clist         = (ull*)(w +       3400000);        // 3,400,000 + 8 MiB
    ull* clist2        = (ull*)(w +      11800000);        // 11,800,000 + 16 MiB

    hipMemsetAsync(rawCnt, 0, 96, stream);
    k_stream<<<dim3(NBLKA, BATCH), dim3(256), 0, stream>>>(scores, rps, p1, clist,
                                                           rawCnt, ovf);
    k_scan1<<<dim3(BATCH), dim3(256), 0, stream>>>(p1, rawCnt, ovf, chist64, csuf64,
                                                   ctrA, meta, K);
    k_fb<<<dim3(NBLKA, BATCH), dim3(256), 0, stream>>>(scores, rps, meta, clist2, rawCnt2);
    k_fine<<<dim3(BATCH), dim3(1024), 0, stream>>>(clist, clist2, rawCnt, rawCnt2,
                                                   meta, red2);
    k_scan2<<<dim3(BATCH), dim3(1024), 0, stream>>>(red2, fhist, fsuf, ctrB, meta, K);
    k_compact<<<dim3(32, BATCH), dim3(256), 0, stream>>>(clist, clist2, rawCnt, rawCnt2,
                                                         meta, csuf64, fsuf, ctrA, ctrB,
                                                         cand);
    k_rank_out<<<dim3(CAP / 256, BATCH), dim3(256), 0, stream>>>(cand, meta, csuf64,
                                                                 chist64, fsuf, fhist,
                                                                 rps, (float*)d_out, K);
}

// Round 9
// 112.429 us; speedup vs baseline: 1.1646x; 1.1646x over previous
//
#include <hip/hip_runtime.h>
#include <stdint.h>

#define BATCH    8
#define NITEMS   1000000
#define NTHR     125000        // NITEMS/8 threads, 8 items each
#define NBLKS    489           // ceil(NTHR/256)
#define NC       64
#define NF       4096
#define NF8      8192          // unified fine space over top-2 coarse bins
#define SBASE    62
#define THRESH   0.96875f      // 62/64, exact in fp32
#define MID63    0.984375f     // 63/64, exact in fp32
#define BUFCAP   512
#define CANDCAP  65536
#define CANDCAP2 262144
#define CAP      32768
#define IMG_W    768.0f
#define IMG_H    432.0f

typedef unsigned long long ull;

static __device__ __forceinline__ float clip0(float v, float hi) {
    return fminf(fmaxf(v, 0.0f), hi);
}
static __device__ __forceinline__ int cbin(float s) {
    int g = (int)(s * (float)NC);
    return g > NC - 1 ? NC - 1 : (g < 0 ? 0 : g);
}
static __device__ __forceinline__ int fbin(float s, int g) {
    int f = (int)(s * (float)(NC * NF)) - g * NF;
    return f > NF - 1 ? NF - 1 : (f < 0 ? 0 : f);
}
static __device__ __forceinline__ unsigned mkbits(float4 box, float s) {
    float x1 = clip0(box.x - box.z * 0.5f, IMG_W);
    float x2 = clip0(box.x + box.z * 0.5f, IMG_W);
    float y1 = clip0(box.y - box.w * 0.5f, IMG_H);
    float y2 = clip0(box.y + box.w * 0.5f, IMG_H);
    bool m = ((x2 - x1) > 16.0f) && ((y2 - y1) > 16.0f);
    return __float_as_uint(m ? s : 0.0f);
}
static __device__ __forceinline__ int g8of(float s) {
    int cb = (s >= MID63) ? 63 : 62;
    return (cb - SBASE) * NF + fbin(s, cb);
}

// ---- kernel 1: scores-only stream (32 MB), append raw top-window candidates ----
__global__ __launch_bounds__(256)
void k_scores(const float* __restrict__ scores,
              ull* __restrict__ clist,
              unsigned* __restrict__ rawCnt,
              unsigned* __restrict__ ovf) {
    __shared__ ull buf[BUFCAP];
    __shared__ unsigned blkCnt, gBase;
    const int b = blockIdx.y, tid = threadIdx.x;
    const int t = blockIdx.x * 256 + tid;
    const int lane = tid & 63;
    if (tid == 0) blkCnt = 0u;
    __syncthreads();
    const float4* sp4 = (const float4*)(scores + (size_t)b * NITEMS);
    float4 a0 = make_float4(0, 0, 0, 0), a1 = make_float4(0, 0, 0, 0);
    const bool act = (t < NTHR);
    if (act) { a0 = sp4[2 * t]; a1 = sp4[2 * t + 1]; }
    __builtin_amdgcn_sched_barrier(0);
    float sv[8] = {a0.x, a0.y, a0.z, a0.w, a1.x, a1.y, a1.z, a1.w};
    const int i0 = t * 8;
    #pragma unroll
    for (int j = 0; j < 8; ++j) {
        bool q = act && (sv[j] >= THRESH);
        ull m = __ballot(q);
        if (m) {
            unsigned pre = (unsigned)__popcll(m & ((1ULL << lane) - 1ULL));
            int leader = __ffsll((long long)m) - 1;
            unsigned bse = 0;
            if (lane == leader) bse = atomicAdd(&blkCnt, (unsigned)__popcll(m));
            bse = (unsigned)__shfl((int)bse, leader);
            if (q) {
                unsigned s2 = bse + pre;
                if (s2 < BUFCAP)
                    buf[s2] = ((ull)__float_as_uint(sv[j]) << 32) |
                              (unsigned)(~(unsigned)(i0 + j));
            }
        }
    }
    __syncthreads();
    unsigned n = blkCnt;
    if (n > BUFCAP) { if (tid == 0) atomicOr(&ovf[b], 1u); n = BUFCAP; }
    if (tid == 0) gBase = atomicAdd(&rawCnt[b], n);
    __syncthreads();
    const unsigned gb = gBase;
    for (unsigned i = tid; i < n; i += 256) {
        unsigned slot = gb + i;
        if (slot < CANDCAP) clist[(size_t)b * CANDCAP + slot] = buf[i];
    }
}

// ---- kernel 2: gather boxes for candidates only, kill masked entries ----
__global__ __launch_bounds__(256)
void k_mask(const float4* __restrict__ rps,
            const unsigned* __restrict__ rawCnt,
            ull* __restrict__ clist) {
    const int b = blockIdx.y;
    unsigned N = rawCnt[b]; if (N > CANDCAP) N = CANDCAP;
    const size_t c0 = (size_t)b * CANDCAP;
    for (unsigned i = blockIdx.x * 256 + threadIdx.x; i < N; i += 64 * 256) {
        ull key = clist[c0 + i];
        unsigned idx = ~((unsigned)key);
        float4 box = rps[(size_t)b * NITEMS + idx];
        float s = __uint_as_float((unsigned)(key >> 32));
        if (!mkbits(box, s)) clist[c0 + i] = 0ull;
    }
}

// ---- kernel 3: 8192-bin hist over survivors + suffix scan + meta ----
__global__ __launch_bounds__(1024)
void k_mid(const ull* __restrict__ clist,
           const unsigned* __restrict__ rawCnt,
           const unsigned* __restrict__ ovf,
           unsigned* __restrict__ fhist8,
           unsigned* __restrict__ fsuf8,
           unsigned* __restrict__ ctrB8,
           unsigned* __restrict__ meta,
           int K) {
    const int b = blockIdx.x, tid = threadIdx.x;
    __shared__ unsigned h[NF8];
    __shared__ unsigned sc[1024];
    for (int k = tid; k < NF8; k += 1024) h[k] = 0u;
    __syncthreads();
    const unsigned rawN = rawCnt[b];
    unsigned N = rawN > CANDCAP ? CANDCAP : rawN;
    const size_t c0 = (size_t)b * CANDCAP;
    for (unsigned i = tid; i < N; i += 1024) {
        ull key = clist[c0 + i];
        if (!key) continue;
        float s = __uint_as_float((unsigned)(key >> 32));
        atomicAdd(&h[g8of(s)], 1u);
    }
    __syncthreads();
    unsigned cw[8], pin[8], run = 0;
    #pragma unroll
    for (int k = 0; k < 8; ++k) {
        cw[k] = h[NF8 - 1 - (tid * 8 + k)];
        run += cw[k]; pin[k] = run;
    }
    sc[tid] = run; __syncthreads();
    unsigned x = run;
    for (int off = 1; off < 1024; off <<= 1) {
        unsigned tv = (tid >= off) ? sc[tid - off] : 0u;
        __syncthreads();
        x += tv; sc[tid] = x;
        __syncthreads();
    }
    const unsigned exclBase = x - run;
    const unsigned total = sc[1023];
    #pragma unroll
    for (int k = 0; k < 8; ++k) {
        int g = NF8 - 1 - (tid * 8 + k);
        unsigned excl = exclBase + pin[k] - cw[k];
        fsuf8[b * NF8 + g] = excl;
        fhist8[b * NF8 + g] = cw[k];
        ctrB8[b * NF8 + g] = 0u;
        if (excl < (unsigned)K && excl + cw[k] >= (unsigned)K) {
            meta[b * 8 + 2] = (unsigned)g;
            meta[b * 8 + 3] = excl + cw[k];
        }
    }
    if (tid == 0) {
        meta[b * 8 + 0] = SBASE;
        meta[b * 8 + 1] = 0u;
        meta[b * 8 + 5] = N;
        meta[b * 8 + 4] = (total >= (unsigned)K && ovf[b] == 0u &&
                           rawN <= (unsigned)CANDCAP) ? 1u : 0u;
        if (total < (unsigned)K) { meta[b * 8 + 2] = 0u; meta[b * 8 + 3] = total; }
    }
}

// ==== generic fallback chain (correctness only; early-exits when fast) ====
__global__ __launch_bounds__(256)
void k_fb_hist(const float* __restrict__ scores,
               const float4* __restrict__ rps,
               const unsigned* __restrict__ meta,
               unsigned* __restrict__ chist64) {
    const int b = blockIdx.y;
    if (meta[b * 8 + 4]) return;
    __shared__ unsigned h1[NC];
    const int tid = threadIdx.x;
    if (tid < NC) h1[tid] = 0u;
    __syncthreads();
    const size_t base = (size_t)b * NITEMS;
    for (int i = blockIdx.x * 256 + tid; i < NITEMS; i += 64 * 256) {
        unsigned bits = mkbits(rps[base + i], scores[base + i]);
        if (bits) atomicAdd(&h1[cbin(__uint_as_float(bits))], 1u);
    }
    __syncthreads();
    if (tid < NC && h1[tid]) atomicAdd(&chist64[b * NC + tid], h1[tid]);
}

__global__ __launch_bounds__(64)
void k_fb_scan1(const unsigned* __restrict__ chist64,
                unsigned* __restrict__ csuf64,
                unsigned* __restrict__ ctrA64,
                unsigned* __restrict__ meta,
                int K) {
    const int b = blockIdx.x, tid = threadIdx.x;
    if (meta[b * 8 + 4]) return;
    __shared__ unsigned sm[NC];
    if (tid < NC) sm[tid] = chist64[b * NC + tid];
    __syncthreads();
    if (tid == 0) {
        unsigned run = 0, cbb = 0, nAb = 0; bool found = false;
        for (int g = NC - 1; g >= 0; --g) {
            unsigned c = sm[g];
            csuf64[b * NC + g] = run;
            if (!found && run < (unsigned)K && run + c >= (unsigned)K) {
                cbb = (unsigned)g; nAb = run; found = true;
            }
            run += c;
        }
        meta[b * 8 + 0] = cbb;
        meta[b * 8 + 1] = nAb;
    }
    if (tid < NC) ctrA64[b * NC + tid] = 0u;
}

__global__ __launch_bounds__(256)
void k_fb_collect(const float* __restrict__ scores,
                  const float4* __restrict__ rps,
                  const unsigned* __restrict__ meta,
                  ull* __restrict__ clist2,
                  unsigned* __restrict__ rawCnt2) {
    const int b = blockIdx.y;
    if (meta[b * 8 + 4]) return;
    const int tid = threadIdx.x, lane = tid & 63;
    const unsigned cbb = meta[b * 8 + 0];
    const size_t base = (size_t)b * NITEMS;
    for (int i = blockIdx.x * 256 + tid; i < NITEMS; i += 64 * 256) {
        unsigned bits = mkbits(rps[base + i], scores[base + i]);
        bool q = bits && ((unsigned)cbin(__uint_as_float(bits)) >= cbb);
        ull m = __ballot(q);
        if (m) {
            unsigned pre = (unsigned)__popcll(m & ((1ULL << lane) - 1ULL));
            int leader = __ffsll((long long)m) - 1;
            unsigned bse = 0;
            if (lane == leader) bse = atomicAdd(&rawCnt2[b], (unsigned)__popcll(m));
            bse = (unsigned)__shfl((int)bse, leader);
            if (q) {
                unsigned slot = bse + pre;
                if (slot < CANDCAP2)
                    clist2[(size_t)b * CANDCAP2 + slot] =
                        ((ull)bits << 32) | (unsigned)(~(unsigned)i);
            }
        }
    }
}

__global__ __launch_bounds__(1024)
void k_fb_finescan(const ull* __restrict__ clist2,
                   const unsigned* __restrict__ rawCnt2,
                   unsigned* __restrict__ fhistF,
                   unsigned* __restrict__ fsufF,
                   unsigned* __restrict__ ctrBF,
                   unsigned* __restrict__ meta,
                   int K) {
    const int b = blockIdx.x, tid = threadIdx.x;
    if (meta[b * 8 + 4]) return;
    __shared__ unsigned h2[NF];
    __shared__ unsigned sc[1024];
    for (int k = tid; k < NF; k += 1024) h2[k] = 0u;
    __syncthreads();
    const unsigned cbb = meta[b * 8 + 0], nAb = meta[b * 8 + 1];
    unsigned N = rawCnt2[b]; if (N > CANDCAP2) N = CANDCAP2;
    for (unsigned i = tid; i < N; i += 1024) {
        unsigned bits = (unsigned)(clist2[(size_t)b * CANDCAP2 + i] >> 32);
        float s = __uint_as_float(bits);
        if ((unsigned)cbin(s) == cbb) atomicAdd(&h2[fbin(s, (int)cbb)], 1u);
    }
    __syncthreads();
    unsigned cw[4], pin[4], run = 0;
    #pragma unroll
    for (int k = 0; k < 4; ++k) {
        cw[k] = h2[NF - 1 - (tid * 4 + k)];
        run += cw[k]; pin[k] = run;
    }
    sc[tid] = run; __syncthreads();
    unsigned x = run;
    for (int off = 1; off < 1024; off <<= 1) {
        unsigned tv = (tid >= off) ? sc[tid - off] : 0u;
        __syncthreads();
        x += tv; sc[tid] = x;
        __syncthreads();
    }
    const unsigned exclBase = x - run;
    const unsigned total = sc[1023];
    #pragma unroll
    for (int k = 0; k < 4; ++k) {
        int g = NF - 1 - (tid * 4 + k);
        unsigned excl = exclBase + pin[k] - cw[k];
        fsufF[b * NF + g] = excl;
        fhistF[b * NF + g] = cw[k];
        ctrBF[b * NF + g] = 0u;
        unsigned t0 = nAb + excl;
        if (t0 < (unsigned)K && t0 + cw[k] >= (unsigned)K) {
            meta[b * 8 + 2] = (unsigned)g;
            meta[b * 8 + 3] = t0 + cw[k];
        }
    }
    if (tid == 0 && nAb + total < (unsigned)K) {
        meta[b * 8 + 2] = 0u;
        meta[b * 8 + 3] = nAb + total;
    }
}

// ---- compact candidates into segmented slots ----
__global__ __launch_bounds__(256)
void k_compact(const ull* __restrict__ clist,
               const ull* __restrict__ clist2,
               const unsigned* __restrict__ rawCnt2,
               const unsigned* __restrict__ meta,
               const unsigned* __restrict__ fsuf8, unsigned* __restrict__ ctrB8,
               const unsigned* __restrict__ csuf64, unsigned* __restrict__ ctrA64,
               const unsigned* __restrict__ fsufF, unsigned* __restrict__ ctrBF,
               ull* __restrict__ cand) {
    const int b = blockIdx.y;
    if (meta[b * 8 + 4]) {
        const unsigned fb8 = meta[b * 8 + 2];
        const unsigned N = meta[b * 8 + 5];
        const size_t c0 = (size_t)b * CANDCAP;
        for (unsigned i = blockIdx.x * 256 + threadIdx.x; i < N; i += gridDim.x * 256) {
            ull key = clist[c0 + i];
            if (!key) continue;
            float s = __uint_as_float((unsigned)(key >> 32));
            int g8 = g8of(s);
            if ((unsigned)g8 < fb8) continue;
            unsigned slot = fsuf8[b * NF8 + g8] + atomicAdd(&ctrB8[b * NF8 + g8], 1u);
            if (slot < CAP) cand[(size_t)b * CAP + slot] = key;
        }
    } else {
        const unsigned cbb = meta[b * 8 + 0], nAb = meta[b * 8 + 1], fb = meta[b * 8 + 2];
        unsigned N = rawCnt2[b]; if (N > CANDCAP2) N = CANDCAP2;
        const size_t c2 = (size_t)b * CANDCAP2;
        for (unsigned i = blockIdx.x * 256 + threadIdx.x; i < N; i += gridDim.x * 256) {
            ull key = clist2[c2 + i];
            if (!key) continue;
            float s = __uint_as_float((unsigned)(key >> 32));
            int g = cbin(s);
            if ((unsigned)g < cbb) continue;
            unsigned slot;
            if ((unsigned)g > cbb) {
                slot = csuf64[b * NC + g] + atomicAdd(&ctrA64[b * NC + g], 1u);
            } else {
                int f = fbin(s, g);
                if ((unsigned)f < fb) continue;
                slot = nAb + fsufF[b * NF + f] + atomicAdd(&ctrBF[b * NF + f], 1u);
            }
            if (slot < CAP) cand[(size_t)b * CAP + slot] = key;
        }
    }
}

// ---- rank within tiny segment, gather, write outputs ----
__global__ __launch_bounds__(256)
void k_rank_out(const ull* __restrict__ cand,
                const unsigned* __restrict__ meta,
                const unsigned* __restrict__ fsuf8, const unsigned* __restrict__ fhist8,
                const unsigned* __restrict__ csuf64, const unsigned* __restrict__ chist64,
                const unsigned* __restrict__ fsufF, const unsigned* __restrict__ fhistF,
                const float4* __restrict__ rps,
                float* __restrict__ out,
                int K) {
    const int b = blockIdx.y;
    unsigned total = meta[b * 8 + 3];
    if (total > CAP) total = CAP;
    const unsigned p = blockIdx.x * 256 + threadIdx.x;
    if (p >= total) return;
    const ull key = cand[(size_t)b * CAP + p];
    const float s = __uint_as_float((unsigned)(key >> 32));
    unsigned sbase, scnt;
    if (meta[b * 8 + 4]) {
        int g8 = g8of(s);
        sbase = fsuf8[b * NF8 + g8];
        scnt  = fhist8[b * NF8 + g8];
    } else {
        const unsigned cbb = meta[b * 8 + 0], nAb = meta[b * 8 + 1];
        int g = cbin(s);
        if ((unsigned)g > cbb) {
            sbase = csuf64[b * NC + g];
            scnt  = chist64[b * NC + g];
        } else {
            int f = fbin(s, g);
            sbase = nAb + fsufF[b * NF + f];
            scnt  = fhistF[b * NF + f];
        }
    }
    unsigned send = sbase + scnt;
    if (send > total) send = total;
    unsigned rank = sbase;
    for (unsigned j = sbase; j < send; j++)
        rank += (cand[(size_t)b * CAP + j] > key) ? 1u : 0u;
    if (rank < (unsigned)K) {
        unsigned idx = ~((unsigned)key);
        if (idx >= (unsigned)NITEMS) idx = 0;
        float4 box = rps[(size_t)b * NITEMS + idx];
        float x1 = clip0(box.x - box.z * 0.5f, IMG_W);
        float x2 = clip0(box.x + box.z * 0.5f, IMG_W);
        float y1 = clip0(box.y - box.w * 0.5f, IMG_H);
        float y2 = clip0(box.y + box.w * 0.5f, IMG_H);
        float nw = x2 - x1, nh = y2 - y1;
        float nx = x1 + nw * 0.5f, ny = y1 + nh * 0.5f;
        ((float4*)out)[(size_t)b * K + rank] = make_float4(nx, ny, nw, nh);
        out[(size_t)BATCH * K * 4 + (size_t)b * K + rank] = s;
    }
}

extern "C" void kernel_launch(void* const* d_in, const int* in_sizes, int n_in,
                              void* d_out, int out_size, void* d_ws, size_t ws_size,
                              hipStream_t stream) {
    const float*  scores = (const float*)d_in[0];
    const float4* rps    = (const float4*)d_in[1];
    const int K = out_size / (BATCH * 5);               // 12000

    // ---- workspace layout (non-overlapping; sizes in comments) ----
    uint8_t* w = (uint8_t*)d_ws;
    ull* clist        = (ull*)(w);                      //          0 + 4,194,304
    ull* cand         = (ull*)(w +  4500000);           //  4,500,000 + 2,097,152
    ull* clist2       = (ull*)(w +  7000000);           //  7,000,000 + 16,777,216
    unsigned* fhist8  = (unsigned*)(w + 24000000);      // 24,000,000 + 262,144
    unsigned* fsuf8   = (unsigned*)(w + 24300000);      // 24,300,000 + 262,144
    unsigned* ctrB8   = (unsigned*)(w + 24600000);      // 24,600,000 + 262,144
    unsigned* meta    = (unsigned*)(w + 24900000);      // 24,900,000 + 256
    unsigned* rawCnt  = (unsigned*)(w + 24901024);      // 32 B ┐
    unsigned* rawCnt2 = (unsigned*)(w + 24901056);      // 32 B │ one 2144-B memset
    unsigned* ovf     = (unsigned*)(w + 24901088);      // 32 B │ (incl. chist64)
    unsigned* chist64 = (unsigned*)(w + 24901120);      // 2048 ┘ ends 24,903,168
    unsigned* csuf64  = (unsigned*)(w + 24910000);      // 24,910,000 + 2,048
    unsigned* ctrA64  = (unsigned*)(w + 24913000);      // 24,913,000 + 2,048
    unsigned* fhistF  = (unsigned*)(w + 24920000);      // 24,920,000 + 131,072
    unsigned* fsufF   = (unsigned*)(w + 25100000);      // 25,100,000 + 131,072
    unsigned* ctrBF   = (unsigned*)(w + 25300000);      // 25,300,000 + 131,072

    hipMemsetAsync(rawCnt, 0, 2144, stream);            // rawCnt..chist64
    k_scores<<<dim3(NBLKS, BATCH), dim3(256), 0, stream>>>(scores, clist, rawCnt, ovf);
    k_mask<<<dim3(64, BATCH), dim3(256), 0, stream>>>(rps, rawCnt, clist);
    k_mid<<<dim3(BATCH), dim3(1024), 0, stream>>>(clist, rawCnt, ovf, fhist8, fsuf8,
                                                  ctrB8, meta, K);
    k_fb_hist<<<dim3(64, BATCH), dim3(256), 0, stream>>>(scores, rps, meta, chist64);
    k_fb_scan1<<<dim3(BATCH), dim3(64), 0, stream>>>(chist64, csuf64, ctrA64, meta, K);
    k_fb_collect<<<dim3(64, BATCH), dim3(256), 0, stream>>>(scores, rps, meta,
                                                            clist2, rawCnt2);
    k_fb_finescan<<<dim3(BATCH), dim3(1024), 0, stream>>>(clist2, rawCnt2, fhistF,
                                                          fsufF, ctrBF, meta, K);
    k_compact<<<dim3(16, BATCH), dim3(256), 0, stream>>>(clist, clist2, rawCnt2, meta,
                                                         fsuf8, ctrB8, csuf64, ctrA64,
                                                         fsufF, ctrBF, cand);
    k_rank_out<<<dim3(CAP / 256, BATCH), dim3(256), 0, stream>>>(cand, meta, fsuf8,
                                                                 fhist8, csuf64, chist64,
                                                                 fsufF, fhistF, rps,
                                                                 (float*)d_out, K);
}

// Round 10
// 91.744 us; speedup vs baseline: 1.4272x; 1.2255x over previous
//
#include <hip/hip_runtime.h>
#include <stdint.h>

#define BATCH    8
#define NITEMS   1000000
#define NTHR     125000        // NITEMS/8 threads, 8 items each
#define NBLKS    489           // ceil(NTHR/256)
#define NC       64
#define NF       4096
#define NF8      8192          // unified fine space over top-2 coarse bins
#define SBASE    62
#define THRESH   0.96875f      // 62/64, exact in fp32
#define MID63    0.984375f     // 63/64, exact in fp32
#define BUFCAP   512
#define CANDCAP  65536         // clist capacity per batch
#define CANDCAP2 262144        // fallback boundary-bin list capacity
#define CAPC     131072        // cand capacity per batch
#define IMG_W    768.0f
#define IMG_H    432.0f

typedef unsigned long long ull;

static __device__ __forceinline__ float clip0(float v, float hi) {
    return fminf(fmaxf(v, 0.0f), hi);
}
static __device__ __forceinline__ int cbin(float s) {
    int g = (int)(s * (float)NC);                   // pow-2 mul: exact, monotone
    return g > NC - 1 ? NC - 1 : (g < 0 ? 0 : g);
}
static __device__ __forceinline__ int fbin(float s, int g) {
    int f = (int)(s * (float)(NC * NF)) - g * NF;   // pow-2 mul: exact, monotone
    return f > NF - 1 ? NF - 1 : (f < 0 ? 0 : f);
}
static __device__ __forceinline__ unsigned mkbits(float4 box, float s) {
    float x1 = clip0(box.x - box.z * 0.5f, IMG_W);
    float x2 = clip0(box.x + box.z * 0.5f, IMG_W);
    float y1 = clip0(box.y - box.w * 0.5f, IMG_H);
    float y2 = clip0(box.y + box.w * 0.5f, IMG_H);
    bool m = ((x2 - x1) > 16.0f) && ((y2 - y1) > 16.0f);
    return __float_as_uint(m ? s : 0.0f);
}
static __device__ __forceinline__ int g8of(float s) {
    int cb = (s >= MID63) ? 63 : 62;
    return (cb - SBASE) * NF + fbin(s, cb);
}

// ---- K1: scores stream + ballot-append + inline mask-gather + global hist ----
__global__ __launch_bounds__(256)
void k_scores(const float* __restrict__ scores,
              const float4* __restrict__ rps,
              ull* __restrict__ clist,
              unsigned* __restrict__ fhist8g,
              unsigned* __restrict__ rawCnt,
              unsigned* __restrict__ ovf) {
    __shared__ ull buf[BUFCAP];
    __shared__ unsigned blkCnt, gBase;
    const int b = blockIdx.y, tid = threadIdx.x;
    const int t = blockIdx.x * 256 + tid;
    const int lane = tid & 63;
    if (tid == 0) blkCnt = 0u;
    __syncthreads();
    const float4* sp4 = (const float4*)(scores + (size_t)b * NITEMS);
    float4 a0 = make_float4(0, 0, 0, 0), a1 = make_float4(0, 0, 0, 0);
    const bool act = (t < NTHR);
    if (act) { a0 = sp4[2 * t]; a1 = sp4[2 * t + 1]; }
    float sv[8] = {a0.x, a0.y, a0.z, a0.w, a1.x, a1.y, a1.z, a1.w};
    const int i0 = t * 8;
    #pragma unroll
    for (int j = 0; j < 8; ++j) {
        bool q = act && (sv[j] >= THRESH);
        ull m = __ballot(q);
        if (m) {
            unsigned pre = (unsigned)__popcll(m & ((1ULL << lane) - 1ULL));
            int leader = __ffsll((long long)m) - 1;
            unsigned bse = 0;
            if (lane == leader) bse = atomicAdd(&blkCnt, (unsigned)__popcll(m));
            bse = (unsigned)__shfl((int)bse, leader);
            if (q) {
                unsigned s2 = bse + pre;
                if (s2 < BUFCAP)
                    buf[s2] = ((ull)__float_as_uint(sv[j]) << 32) |
                              (unsigned)(~(unsigned)(i0 + j));
            }
        }
    }
    __syncthreads();
    unsigned n = blkCnt;
    if (n > BUFCAP) { if (tid == 0) atomicOr(&ovf[b], 1u); n = BUFCAP; }
    if (tid == 0) gBase = atomicAdd(&rawCnt[b], n);
    __syncthreads();
    const unsigned gb = gBase;
    for (unsigned i = tid; i < n; i += 256) {
        unsigned slot = gb + i;
        if (slot >= CANDCAP) break;            // global overflow → K2 falls back
        ull key = buf[i];
        unsigned idx = ~((unsigned)key);
        float4 box = rps[(size_t)b * NITEMS + idx];
        float s = __uint_as_float((unsigned)(key >> 32));
        if (mkbits(box, s)) {
            atomicAdd(&fhist8g[b * NF8 + g8of(s)], 1u);
            clist[(size_t)b * CANDCAP + slot] = key;
        } else {
            clist[(size_t)b * CANDCAP + slot] = 0ull;
        }
    }
}

// ---- K2: per-batch mega-kernel: scan + compact (fast) OR full fallback ----
__global__ __launch_bounds__(1024)
void k_mid(const float* __restrict__ scores,
           const float4* __restrict__ rps,
           const ull* __restrict__ clist,
           ull* __restrict__ clist2,
           const unsigned* __restrict__ rawCnt,
           const unsigned* __restrict__ ovf,
           const unsigned* __restrict__ fhist8g,
           unsigned* __restrict__ fsuf8g,
           unsigned* __restrict__ csuf64g,
           unsigned* __restrict__ chist64g,
           unsigned* __restrict__ fsufFg,
           unsigned* __restrict__ fhistFg,
           unsigned* __restrict__ meta,
           ull* __restrict__ cand,
           int K) {
    const int b = blockIdx.x, tid = threadIdx.x;
    __shared__ unsigned h[NF8];                 // 32 KB: suffix→slot-counter
    __shared__ unsigned sc[1024];
    __shared__ unsigned smallA[NC], smallB[NC];
    __shared__ unsigned s_fb8, s_tot, s_cbb, s_nab, s_n2;

    // ---- scan the K1-built 8192-bin histogram ----
    unsigned cw[8], pin[8], run = 0;
    const unsigned* hb = fhist8g + b * NF8;
    #pragma unroll
    for (int k = 0; k < 8; ++k) {
        cw[k] = hb[NF8 - 1 - (tid * 8 + k)];
        run += cw[k]; pin[k] = run;
    }
    sc[tid] = run; __syncthreads();
    unsigned x = run;
    for (int off = 1; off < 1024; off <<= 1) {
        unsigned tv = (tid >= off) ? sc[tid - off] : 0u;
        __syncthreads();
        x += tv; sc[tid] = x;
        __syncthreads();
    }
    const unsigned exclBase = x - run;
    const unsigned alive = sc[1023];
    if (tid == 0) { s_fb8 = 0u; s_tot = alive; }
    __syncthreads();
    #pragma unroll
    for (int k = 0; k < 8; ++k) {
        int g = NF8 - 1 - (tid * 8 + k);
        unsigned excl = exclBase + pin[k] - cw[k];
        fsuf8g[b * NF8 + g] = excl;
        h[g] = excl;                            // slot counter base
        if (excl < (unsigned)K && excl + cw[k] >= (unsigned)K) {
            s_fb8 = (unsigned)g; s_tot = excl + cw[k];
        }
    }
    __syncthreads();
    const unsigned rawN0 = rawCnt[b];
    unsigned N = rawN0 > CANDCAP ? CANDCAP : rawN0;
    const bool fast = (alive >= (unsigned)K) && (ovf[b] == 0u) &&
                      (rawN0 <= (unsigned)CANDCAP) && (s_tot <= (unsigned)CAPC);
    if (tid == 0) {
        meta[b * 8 + 4] = fast ? 1u : 0u;
        meta[b * 8 + 2] = s_fb8;
        meta[b * 8 + 3] = s_tot;
    }
    __syncthreads();
    if (fast) {
        const unsigned fb8v = s_fb8;
        const size_t c0 = (size_t)b * CANDCAP;
        for (unsigned i = tid; i < N; i += 1024) {
            ull key = clist[c0 + i];
            if (!key) continue;
            float s = __uint_as_float((unsigned)(key >> 32));
            int g8 = g8of(s);
            if ((unsigned)g8 < fb8v) continue;
            unsigned slot = atomicAdd(&h[g8], 1u);
            if (slot < CAPC) cand[(size_t)b * CAPC + slot] = key;
        }
        return;
    }
    // ---- generic fallback (block-local, correctness-only) ----
    if (tid < NC) smallA[tid] = 0u;
    __syncthreads();
    const size_t base = (size_t)b * NITEMS;
    for (int i = tid; i < NITEMS; i += 1024) {
        unsigned bits = mkbits(rps[base + i], scores[base + i]);
        if (bits) atomicAdd(&smallA[cbin(__uint_as_float(bits))], 1u);
    }
    __syncthreads();
    if (tid == 0) {
        unsigned runc = 0, cbb = 0, nab = 0; bool found = false;
        for (int g = NC - 1; g >= 0; --g) {
            unsigned c = smallA[g];
            csuf64g[b * NC + g] = runc; chist64g[b * NC + g] = c;
            smallB[g] = runc;
            if (!found && runc < (unsigned)K && runc + c >= (unsigned)K) {
                cbb = (unsigned)g; nab = runc; found = true;
            }
            runc += c;
        }
        s_cbb = cbb; s_nab = nab; s_n2 = 0u;
        meta[b * 8 + 0] = cbb; meta[b * 8 + 1] = nab;
    }
    __syncthreads();
    const unsigned cbb = s_cbb, nab = s_nab;
    if (tid < NC) smallA[tid] = smallB[tid];    // above-bin slot counters
    for (int k = tid; k < NF; k += 1024) h[k] = 0u;
    __syncthreads();
    for (int i = tid; i < NITEMS; i += 1024) {
        unsigned bits = mkbits(rps[base + i], scores[base + i]);
        if (!bits) continue;
        float s = __uint_as_float(bits);
        int g = cbin(s);
        if ((unsigned)g < cbb) continue;
        ull key = ((ull)bits << 32) | (unsigned)(~(unsigned)i);
        if ((unsigned)g > cbb) {
            unsigned slot = atomicAdd(&smallA[g], 1u);
            if (slot < CAPC) cand[(size_t)b * CAPC + slot] = key;
        } else {
            unsigned s2 = atomicAdd(&s_n2, 1u);
            if (s2 < CANDCAP2) clist2[(size_t)b * CANDCAP2 + s2] = key;
            atomicAdd(&h[fbin(s, (int)cbb)], 1u);
        }
    }
    __syncthreads();
    unsigned n2 = s_n2 > CANDCAP2 ? CANDCAP2 : s_n2;
    unsigned fcw[4], fpin[4], frun = 0;
    #pragma unroll
    for (int k = 0; k < 4; ++k) {
        fcw[k] = h[NF - 1 - (tid * 4 + k)];
        frun += fcw[k]; fpin[k] = frun;
    }
    sc[tid] = frun; __syncthreads();
    unsigned fx = frun;
    for (int off = 1; off < 1024; off <<= 1) {
        unsigned tv = (tid >= off) ? sc[tid - off] : 0u;
        __syncthreads();
        fx += tv; sc[tid] = fx;
        __syncthreads();
    }
    const unsigned fexcl = fx - frun;
    const unsigned ftot = sc[1023];
    if (tid == 0) { s_fb8 = 0u; s_tot = nab + ftot; }
    __syncthreads();
    #pragma unroll
    for (int k = 0; k < 4; ++k) {
        int g = NF - 1 - (tid * 4 + k);
        unsigned excl = fexcl + fpin[k] - fcw[k];
        fsufFg[b * NF + g] = excl; fhistFg[b * NF + g] = fcw[k];
        unsigned t0 = nab + excl;
        if (t0 < (unsigned)K && t0 + fcw[k] >= (unsigned)K) {
            s_fb8 = (unsigned)g; s_tot = t0 + fcw[k];
        }
        h[g] = nab + excl;                      // slot counter base
    }
    __syncthreads();
    if (tid == 0) { meta[b * 8 + 2] = s_fb8; meta[b * 8 + 3] = s_tot; }
    __syncthreads();
    const unsigned fbv = s_fb8;
    for (unsigned i = tid; i < n2; i += 1024) {
        ull key = clist2[(size_t)b * CANDCAP2 + i];
        unsigned bits = (unsigned)(key >> 32);
        float s = __uint_as_float(bits);
        int f = fbin(s, (int)cbb);
        if ((unsigned)f < fbv) continue;
        unsigned slot = atomicAdd(&h[f], 1u);
        if (slot < CAPC) cand[(size_t)b * CAPC + slot] = key;
    }
}

// ---- K3: rank within tiny segment, gather, write outputs ----
__global__ __launch_bounds__(256)
void k_rank_out(const ull* __restrict__ cand,
                const unsigned* __restrict__ meta,
                const unsigned* __restrict__ fsuf8g,
                const unsigned* __restrict__ fhist8g,
                const unsigned* __restrict__ csuf64g,
                const unsigned* __restrict__ chist64g,
                const unsigned* __restrict__ fsufFg,
                const unsigned* __restrict__ fhistFg,
                const float4* __restrict__ rps,
                float* __restrict__ out,
                int K) {
    const int b = blockIdx.y;
    unsigned total = meta[b * 8 + 3];
    if (total > CAPC) total = CAPC;
    const unsigned fast = meta[b * 8 + 4];
    for (unsigned p = blockIdx.x * 256 + threadIdx.x; p < total;
         p += gridDim.x * 256) {
        const ull key = cand[(size_t)b * CAPC + p];
        const float s = __uint_as_float((unsigned)(key >> 32));
        unsigned sbase, scnt;
        if (fast) {
            int g8 = g8of(s);
            sbase = fsuf8g[b * NF8 + g8];
            scnt  = fhist8g[b * NF8 + g8];
        } else {
            const unsigned cbb = meta[b * 8 + 0], nab = meta[b * 8 + 1];
            int g = cbin(s);
            if ((unsigned)g > cbb) {
                sbase = csuf64g[b * NC + g];
                scnt  = chist64g[b * NC + g];
            } else {
                int f = fbin(s, (int)g);
                sbase = nab + fsufFg[b * NF + f];
                scnt  = fhistFg[b * NF + f];
            }
        }
        unsigned send = sbase + scnt;
        if (send > total) send = total;
        unsigned rank = sbase;
        for (unsigned j = sbase; j < send; ++j)
            rank += (cand[(size_t)b * CAPC + j] > key) ? 1u : 0u;
        if (rank < (unsigned)K) {
            unsigned idx = ~((unsigned)key);
            if (idx >= (unsigned)NITEMS) idx = 0;
            float4 box = rps[(size_t)b * NITEMS + idx];
            float x1 = clip0(box.x - box.z * 0.5f, IMG_W);
            float x2 = clip0(box.x + box.z * 0.5f, IMG_W);
            float y1 = clip0(box.y - box.w * 0.5f, IMG_H);
            float y2 = clip0(box.y + box.w * 0.5f, IMG_H);
            float nw = x2 - x1, nh = y2 - y1;
            float nx = x1 + nw * 0.5f, ny = y1 + nh * 0.5f;
            ((float4*)out)[(size_t)b * K + rank] = make_float4(nx, ny, nw, nh);
            out[(size_t)BATCH * K * 4 + (size_t)b * K + rank] = s;
        }
    }
}

extern "C" void kernel_launch(void* const* d_in, const int* in_sizes, int n_in,
                              void* d_out, int out_size, void* d_ws, size_t ws_size,
                              hipStream_t stream) {
    const float*  scores = (const float*)d_in[0];
    const float4* rps    = (const float4*)d_in[1];
    const int K = out_size / (BATCH * 5);               // 12000

    // ---- workspace layout (non-overlapping; sizes verified) ----
    uint8_t* w = (uint8_t*)d_ws;
    ull* clist        = (ull*)(w);                      //          0 + 4,194,304
    ull* cand         = (ull*)(w +  4500000);           //  4,500,000 + 8,388,608
    ull* clist2       = (ull*)(w + 13000000);           // 13,000,000 + 16,777,216
    unsigned* fhist8g = (unsigned*)(w + 30000000);      // 30,000,000 + 262,144 ┐ one
    unsigned* rawCnt  = (unsigned*)(w + 30262144);      //         32          │ memset
    unsigned* ovf     = (unsigned*)(w + 30262176);      //         32          ┘ 262,208
    unsigned* fsuf8g  = (unsigned*)(w + 30400000);      // 30,400,000 + 262,144
    unsigned* meta    = (unsigned*)(w + 30700000);      // 30,700,000 + 256
    unsigned* csuf64g = (unsigned*)(w + 30701000);      // 30,701,000 + 2,048
    unsigned* chist64g= (unsigned*)(w + 30704000);      // 30,704,000 + 2,048
    unsigned* fsufFg  = (unsigned*)(w + 30710000);      // 30,710,000 + 131,072
    unsigned* fhistFg = (unsigned*)(w + 30850000);      // 30,850,000 + 131,072

    hipMemsetAsync(fhist8g, 0, 262208, stream);
    k_scores<<<dim3(NBLKS, BATCH), dim3(256), 0, stream>>>(scores, rps, clist,
                                                           fhist8g, rawCnt, ovf);
    k_mid<<<dim3(BATCH), dim3(1024), 0, stream>>>(scores, rps, clist, clist2,
                                                  rawCnt, ovf, fhist8g, fsuf8g,
                                                  csuf64g, chist64g, fsufFg, fhistFg,
                                                  meta, cand, K);
    k_rank_out<<<dim3(128, BATCH), dim3(256), 0, stream>>>(cand, meta, fsuf8g, fhist8g,
                                                           csuf64g, chist64g, fsufFg,
                                                           fhistFg, rps,
                                                           (float*)d_out, K);
}